// Round 8
// baseline (149.080 us; speedup 1.0000x reference)
//
#include <hip/hip_runtime.h>

// FuzzySystemLayer, single fused kernel, software-pipelined over b-tiles.
// B=262144, C=256, D=64, O=8 (fp32).
// GEMM1 in fp16 (32x32x16_f16): acc[c_row, b_col] = log2-domain exponent
//   e = (2*x.c)*k - k*x^2 - k*c^2,  k = log2(e)/(2 w^2)
//   5 K-blocks: 4x [A=fp16(2k*c) x B=fp16(x)] + 1 affine block (hi/lo fp16
//   splits of k, x^2, k*c^2; pair error ~2^-22).
// GEMM2 in bf16 (memb spans 2^-40..2^-200: fp16 would flush to zero).
//   out2[o,b] = W'^T @ memb, W' row 8 = ones -> normalizer.
// Cluster rows permuted by swap23 so exp2(acc) registers ARE GEMM2 B-fragments.
// R2 lesson: no local array indexed by runtime var (scratch demotion).
// R4 lesson: fragment loads from L2 were the latency wall -> LDS staging.
// R6 lesson: x B-slice is h-dependent: float4 idx 4*kd + 2*h (+1).
// R7 lesson: one co-resident generation = load phase and compute phase ADD
//   (~25 us). This version: 256 blocks, 4 b-tiles/wave, next tile's x loads
//   issued before current tile's compute -> continuous memory streaming.

#define NB 262144
#define NC 256
#define ND 64
#define NO 8

typedef __attribute__((ext_vector_type(8))) short short8;
typedef __attribute__((ext_vector_type(8))) _Float16 half8;
typedef __attribute__((ext_vector_type(16))) float floatx16;

// LDS layout in shorts:
//   A (fp16):  ((t*5 + idx)*64 + lane)*8 + j   idx 0..3 = 2k*c, idx 4 = affine
//   W (bf16):  20480 + (k2*64 + lane)*8 + j    k2 = 0..15
#define WOFF 20480
#define WS_SHORTS 28672  // 56 KB

__device__ inline unsigned short f2bf(float f) {
    unsigned u = __builtin_bit_cast(unsigned, f);
    u = u + 0x7FFFu + ((u >> 16) & 1u);
    return (unsigned short)(u >> 16);
}

struct Raw8 { float4 r0, r1, r2, r3, r4, r5, r6, r7; };
struct XF { half8 k0, k1, k2, k3, f12; };

__device__ __forceinline__ Raw8 load_x(const float* __restrict__ xrow, int h) {
    const float4* xp = (const float4*)xrow;
    Raw8 r;
    r.r0 = xp[0 + 2 * h]; r.r1 = xp[1 + 2 * h];
    r.r2 = xp[4 + 2 * h]; r.r3 = xp[5 + 2 * h];
    r.r4 = xp[8 + 2 * h]; r.r5 = xp[9 + 2 * h];
    r.r6 = xp[12 + 2 * h]; r.r7 = xp[13 + 2 * h];
    return r;
}

__device__ __forceinline__ half8 cvt8(float4 a, float4 b, float& part) {
    float v[8] = {a.x, a.y, a.z, a.w, b.x, b.y, b.z, b.w};
    half8 hh;
#pragma unroll
    for (int j = 0; j < 8; ++j) {
        part = fmaf(v[j], v[j], part);
        hh[j] = (_Float16)v[j];
    }
    return hh;
}

__device__ __forceinline__ XF convert_x(const Raw8& r, int h) {
    float part = 0.0f;
    XF f;
    f.k0 = cvt8(r.r0, r.r1, part);
    f.k1 = cvt8(r.r2, r.r3, part);
    f.k2 = cvt8(r.r4, r.r5, part);
    f.k3 = cvt8(r.r6, r.r7, part);
    float xsq = part + __shfl_xor(part, 32, 64);
    float sh = (float)(_Float16)xsq;
    float sl = xsq - sh;
    half8 ff;
#pragma unroll
    for (int j = 0; j < 8; ++j) ff[j] = (_Float16)0.0f;
    if (h == 0) {
        ff[0] = (_Float16)sh;
        ff[1] = (_Float16)sl;
        ff[2] = (_Float16)sh;
        ff[3] = (_Float16)1.0f;
        ff[4] = (_Float16)1.0f;
    }
    f.f12 = ff;
    return f;
}

__device__ __forceinline__ void compute_btile(const short* lds_s, int lane, int h,
                                              const XF& xf, float* __restrict__ outp) {
    floatx16 acc2;
#pragma unroll
    for (int i = 0; i < 16; ++i) acc2[i] = 0.0f;

#pragma unroll
    for (int t = 0; t < 8; ++t) {
        const half8 A0 = *(const half8*)&lds_s[((t * 5 + 0) * 64 + lane) * 8];
        const half8 A1 = *(const half8*)&lds_s[((t * 5 + 1) * 64 + lane) * 8];
        const half8 A2 = *(const half8*)&lds_s[((t * 5 + 2) * 64 + lane) * 8];
        const half8 A3 = *(const half8*)&lds_s[((t * 5 + 3) * 64 + lane) * 8];
        const half8 C12 = *(const half8*)&lds_s[((t * 5 + 4) * 64 + lane) * 8];
        const short8 w0 = *(const short8*)&lds_s[WOFF + ((2 * t + 0) * 64 + lane) * 8];
        const short8 w1 = *(const short8*)&lds_s[WOFF + ((2 * t + 1) * 64 + lane) * 8];

        floatx16 acc;
#pragma unroll
        for (int i = 0; i < 16; ++i) acc[i] = 0.0f;
        acc = __builtin_amdgcn_mfma_f32_32x32x16_f16(A0, xf.k0, acc, 0, 0, 0);
        acc = __builtin_amdgcn_mfma_f32_32x32x16_f16(A1, xf.k1, acc, 0, 0, 0);
        acc = __builtin_amdgcn_mfma_f32_32x32x16_f16(A2, xf.k2, acc, 0, 0, 0);
        acc = __builtin_amdgcn_mfma_f32_32x32x16_f16(A3, xf.k3, acc, 0, 0, 0);
        acc = __builtin_amdgcn_mfma_f32_32x32x16_f16(C12, xf.f12, acc, 0, 0, 0);

        // exp2 -> bf16 (RTZ) two-at-a-time via v_perm
        unsigned p0 = __builtin_bit_cast(unsigned, __builtin_amdgcn_exp2f(acc[0]));
        unsigned p1 = __builtin_bit_cast(unsigned, __builtin_amdgcn_exp2f(acc[1]));
        unsigned p2 = __builtin_bit_cast(unsigned, __builtin_amdgcn_exp2f(acc[2]));
        unsigned p3 = __builtin_bit_cast(unsigned, __builtin_amdgcn_exp2f(acc[3]));
        unsigned p4 = __builtin_bit_cast(unsigned, __builtin_amdgcn_exp2f(acc[4]));
        unsigned p5 = __builtin_bit_cast(unsigned, __builtin_amdgcn_exp2f(acc[5]));
        unsigned p6 = __builtin_bit_cast(unsigned, __builtin_amdgcn_exp2f(acc[6]));
        unsigned p7 = __builtin_bit_cast(unsigned, __builtin_amdgcn_exp2f(acc[7]));
        unsigned p8 = __builtin_bit_cast(unsigned, __builtin_amdgcn_exp2f(acc[8]));
        unsigned p9 = __builtin_bit_cast(unsigned, __builtin_amdgcn_exp2f(acc[9]));
        unsigned pa = __builtin_bit_cast(unsigned, __builtin_amdgcn_exp2f(acc[10]));
        unsigned pb = __builtin_bit_cast(unsigned, __builtin_amdgcn_exp2f(acc[11]));
        unsigned pc = __builtin_bit_cast(unsigned, __builtin_amdgcn_exp2f(acc[12]));
        unsigned pd = __builtin_bit_cast(unsigned, __builtin_amdgcn_exp2f(acc[13]));
        unsigned pe = __builtin_bit_cast(unsigned, __builtin_amdgcn_exp2f(acc[14]));
        unsigned pf = __builtin_bit_cast(unsigned, __builtin_amdgcn_exp2f(acc[15]));
        uint4 q0, q1;
        q0.x = __builtin_amdgcn_perm(p1, p0, 0x07060302u);
        q0.y = __builtin_amdgcn_perm(p3, p2, 0x07060302u);
        q0.z = __builtin_amdgcn_perm(p5, p4, 0x07060302u);
        q0.w = __builtin_amdgcn_perm(p7, p6, 0x07060302u);
        q1.x = __builtin_amdgcn_perm(p9, p8, 0x07060302u);
        q1.y = __builtin_amdgcn_perm(pb, pa, 0x07060302u);
        q1.z = __builtin_amdgcn_perm(pd, pc, 0x07060302u);
        q1.w = __builtin_amdgcn_perm(pf, pe, 0x07060302u);
        short8 pf0 = __builtin_bit_cast(short8, q0);
        short8 pf1 = __builtin_bit_cast(short8, q1);

        acc2 = __builtin_amdgcn_mfma_f32_32x32x16_bf16(w0, pf0, acc2, 0, 0, 0);
        acc2 = __builtin_amdgcn_mfma_f32_32x32x16_bf16(w1, pf1, acc2, 0, 0, 0);
    }

    float S = acc2[4];  // row 8 (normalizer) lives at h==0, reg 4
    float Sp = __shfl_xor(S, 32, 64);
    if (h) S = Sp;
    float inv = 1.0f / S;
    float4 r;
    r.x = acc2[0] * inv;
    r.y = acc2[1] * inv;
    r.z = acc2[2] * inv;
    r.w = acc2[3] * inv;
    ((float4*)outp)[h] = r;  // h=0: o=0..3, h=1: o=4..7
}

__global__ __launch_bounds__(512, 2) void fuzzy_main(
    const float* __restrict__ x,
    const float* __restrict__ centers,
    const float* __restrict__ widths,
    const float* __restrict__ W,
    float* __restrict__ out) {
    __shared__ short lds_s[WS_SHORTS];

    const int tid = threadIdx.x;
    const int wave = tid >> 6;
    const int lane = tid & 63;
    const int col = lane & 31;
    const int h = lane >> 5;
    const int bbase = (blockIdx.x * 8 + wave) * 128;  // 128 b-columns per wave

    const float* xr0p = x + (size_t)(bbase + 0 * 32 + col) * ND;
    const float* xr1p = x + (size_t)(bbase + 1 * 32 + col) * ND;
    const float* xr2p = x + (size_t)(bbase + 2 * 32 + col) * ND;
    const float* xr3p = x + (size_t)(bbase + 3 * 32 + col) * ND;
    float* o0 = out + (size_t)(bbase + 0 * 32 + col) * NO;
    float* o1 = out + (size_t)(bbase + 1 * 32 + col) * NO;
    float* o2 = out + (size_t)(bbase + 2 * 32 + col) * NO;
    float* o3 = out + (size_t)(bbase + 3 * 32 + col) * NO;

    // ---- issue first two tiles' x loads (long latency, consumed later) ----
    Raw8 ra = load_x(xr0p, h);
    Raw8 rb = load_x(xr1p, h);

    // ---- fused prep: wave t builds tile t's fragments into LDS ----
    {
        const int t = wave;
        // cluster at GEMM1 row `col` of tile t: swap bits 2<->3 (self-inverse)
        const int c = 32 * t + ((col & 19) | ((col & 4) << 1) | ((col & 8) >> 1));
        const float* cr = centers + c * ND;
        float vv[4][8];
        float part = 0.0f;
#pragma unroll
        for (int kd = 0; kd < 4; ++kd) {
            const float4* p = (const float4*)(cr + kd * 16 + h * 8);
            float4 a0 = p[0], a1 = p[1];
            vv[kd][0] = a0.x; vv[kd][1] = a0.y; vv[kd][2] = a0.z; vv[kd][3] = a0.w;
            vv[kd][4] = a1.x; vv[kd][5] = a1.y; vv[kd][6] = a1.z; vv[kd][7] = a1.w;
#pragma unroll
            for (int j = 0; j < 8; ++j) part = fmaf(vv[kd][j], vv[kd][j], part);
        }
        float csq = part + __shfl_xor(part, 32, 64);
        float w = widths[c];
        float kk = 1.4426950408889634f / (2.0f * w * w);  // log2(e)/(2w^2)

#pragma unroll
        for (int kd = 0; kd < 4; ++kd) {
            half8 ah;
#pragma unroll
            for (int j = 0; j < 8; ++j) ah[j] = (_Float16)(2.0f * kk * vv[kd][j]);
            *(half8*)&lds_s[((t * 5 + kd) * 64 + lane) * 8] = ah;
        }
        // affine block (idx 4), nonzero only on h==0:
        half8 av;
#pragma unroll
        for (int j = 0; j < 8; ++j) av[j] = (_Float16)0.0f;
        if (h == 0) {
            float kh = (float)(_Float16)kk;
            float kl = kk - kh;
            float Bc = csq * kk;
            float Bh = (float)(_Float16)Bc;
            float Bl = Bc - Bh;
            av[0] = (_Float16)(-kh);
            av[1] = (_Float16)(-kh);
            av[2] = (_Float16)(-kl);
            av[3] = (_Float16)(-Bh);
            av[4] = (_Float16)(-Bl);
        }
        *(half8*)&lds_s[((t * 5 + 4) * 64 + lane) * 8] = av;

        // W' fragments (bf16): A[m=o][k=c]; o=col; row 8 = ones (normalizer)
#pragma unroll
        for (int q = 0; q < 2; ++q) {
            int k2 = 2 * t + q;
            short8 wf;
#pragma unroll
            for (int j = 0; j < 8; ++j) {
                int c2 = k2 * 16 + h * 8 + j;  // natural order (perm self-inverts)
                float val = (col < NO) ? W[c2 * NO + col] : (col == 8 ? 1.0f : 0.0f);
                wf[j] = (short)f2bf(val);
            }
            *(short8*)&lds_s[WOFF + (k2 * 64 + lane) * 8] = wf;
        }
    }

    XF x0 = convert_x(ra, h);  // waits on ra only
    __syncthreads();

    // ---- pipelined b-tiles: issue tile u+1 loads before computing tile u ----
    Raw8 rc = load_x(xr2p, h);
    compute_btile(lds_s, lane, h, x0, o0);

    XF x1 = convert_x(rb, h);
    Raw8 rd = load_x(xr3p, h);
    compute_btile(lds_s, lane, h, x1, o1);

    XF x2 = convert_x(rc, h);
    compute_btile(lds_s, lane, h, x2, o2);

    XF x3 = convert_x(rd, h);
    compute_btile(lds_s, lane, h, x3, o3);
}

extern "C" void kernel_launch(void* const* d_in, const int* in_sizes, int n_in,
                              void* d_out, int out_size, void* d_ws, size_t ws_size,
                              hipStream_t stream) {
    const float* x       = (const float*)d_in[0];  // [B, D]
    const float* centers = (const float*)d_in[1];  // [C, D]
    const float* widths  = (const float*)d_in[2];  // [C]
    const float* W       = (const float*)d_in[3];  // [C, O]
    float* out = (float*)d_out;
    (void)d_ws; (void)ws_size;

    // 256 blocks x 512 threads; each wave: 128 b-columns (4 pipelined tiles)
    fuzzy_main<<<NB / 1024, 512, 0, stream>>>(x, centers, widths, W, out);
}

// Round 9
// 111.817 us; speedup vs baseline: 1.3333x; 1.3333x over previous
//
#include <hip/hip_runtime.h>

// FuzzySystemLayer, single fused kernel. B=262144, C=256, D=64, O=8 (fp32).
// GEMM1 in fp16 (32x32x16_f16): acc[c_row, b_col] = log2-domain exponent
//   e = (2*x.c)*k - k*x^2 - k*c^2,  k = log2(e)/(2 w^2)
//   5 K-blocks: 4x [A=fp16(2k*c) x B=fp16(x)] + 1 affine block (hi/lo fp16
//   splits of k, x^2, k*c^2; pair error ~2^-22).
// GEMM2 in bf16 (memb spans 2^-40..2^-200: fp16 would flush to zero).
//   out2[o,b] = W'^T @ memb, W' row 8 = ones -> normalizer.
// Cluster rows permuted by swap23 so exp2(acc) registers ARE GEMM2 B-fragments.
// R2 lesson: no local array indexed by runtime var (scratch demotion).
// R4 lesson: fragment loads from L2 were the latency wall -> LDS staging.
// R6 lesson: x B-slice is h-dependent: float4 idx 4*kd + 2*h (+1).
// R7 lesson: one co-resident generation -> load & compute phases ADD.
// R8 lesson: register-level pipelining (2 Raw8 live across compute) spills
//   (110 MB scratch writes). Overlap must come from BLOCK TURNOVER instead:
// R9: 1 b-tile/wave, 1024 blocks, 2 resident/CU, 4 generations/CU — a fresh
//   block's load+prep phase overlaps its sibling's compute phase. Zero extra
//   register pressure vs R7.

#define NB 262144
#define NC 256
#define ND 64
#define NO 8

typedef __attribute__((ext_vector_type(8))) short short8;
typedef __attribute__((ext_vector_type(8))) _Float16 half8;
typedef __attribute__((ext_vector_type(16))) float floatx16;

// LDS layout in shorts:
//   A (fp16):  ((t*5 + idx)*64 + lane)*8 + j   idx 0..3 = 2k*c, idx 4 = affine
//   W (bf16):  20480 + (k2*64 + lane)*8 + j    k2 = 0..15
#define WOFF 20480
#define WS_SHORTS 28672  // 56 KB

__device__ inline unsigned short f2bf(float f) {
    unsigned u = __builtin_bit_cast(unsigned, f);
    u = u + 0x7FFFu + ((u >> 16) & 1u);
    return (unsigned short)(u >> 16);
}

__global__ __launch_bounds__(512, 4) void fuzzy_main(
    const float* __restrict__ x,
    const float* __restrict__ centers,
    const float* __restrict__ widths,
    const float* __restrict__ W,
    float* __restrict__ out) {
    __shared__ short lds_s[WS_SHORTS];

    const int tid = threadIdx.x;
    const int wave = tid >> 6;
    const int lane = tid & 63;
    const int col = lane & 31;
    const int h = lane >> 5;
    const int b = (blockIdx.x * 8 + wave) * 32 + col;  // this lane's batch row

    // ---- issue raw x loads first (long-latency; convert after prep) ----
    // Lane's B-fragment slice for K-block kd is dims [kd*16 + h*8, +8):
    // float4 indices 4*kd + 2*h and 4*kd + 2*h + 1.
    float4 xr[8];
    {
        const float4* xp = (const float4*)(x + (size_t)b * ND);
#pragma unroll
        for (int kd = 0; kd < 4; ++kd) {
            xr[2 * kd + 0] = xp[4 * kd + 2 * h + 0];
            xr[2 * kd + 1] = xp[4 * kd + 2 * h + 1];
        }
    }

    // ---- fused prep: wave t builds tile t's fragments into LDS ----
    {
        const int t = wave;
        // cluster at GEMM1 row `col` of tile t: swap bits 2<->3 (self-inverse)
        const int c = 32 * t + ((col & 19) | ((col & 4) << 1) | ((col & 8) >> 1));
        const float* cr = centers + c * ND;
        float vv[4][8];
        float part = 0.0f;
#pragma unroll
        for (int kd = 0; kd < 4; ++kd) {
            const float4* p = (const float4*)(cr + kd * 16 + h * 8);
            float4 a0 = p[0], a1 = p[1];
            vv[kd][0] = a0.x; vv[kd][1] = a0.y; vv[kd][2] = a0.z; vv[kd][3] = a0.w;
            vv[kd][4] = a1.x; vv[kd][5] = a1.y; vv[kd][6] = a1.z; vv[kd][7] = a1.w;
#pragma unroll
            for (int j = 0; j < 8; ++j) part = fmaf(vv[kd][j], vv[kd][j], part);
        }
        float csq = part + __shfl_xor(part, 32, 64);
        float w = widths[c];
        float kk = 1.4426950408889634f / (2.0f * w * w);  // log2(e)/(2w^2)

#pragma unroll
        for (int kd = 0; kd < 4; ++kd) {
            half8 ah;
#pragma unroll
            for (int j = 0; j < 8; ++j) ah[j] = (_Float16)(2.0f * kk * vv[kd][j]);
            *(half8*)&lds_s[((t * 5 + kd) * 64 + lane) * 8] = ah;
        }
        // affine block (idx 4), nonzero only on h==0:
        // A = [-k_h, -k_h, -k_l, -(kc^2)_h, -(kc^2)_l, 0,0,0]
        // pairs B = [x2_h, x2_l, x2_h, 1, 1, 0,0,0]
        half8 av;
#pragma unroll
        for (int j = 0; j < 8; ++j) av[j] = (_Float16)0.0f;
        if (h == 0) {
            float kh = (float)(_Float16)kk;
            float kl = kk - kh;
            float Bc = csq * kk;
            float Bh = (float)(_Float16)Bc;
            float Bl = Bc - Bh;
            av[0] = (_Float16)(-kh);
            av[1] = (_Float16)(-kh);
            av[2] = (_Float16)(-kl);
            av[3] = (_Float16)(-Bh);
            av[4] = (_Float16)(-Bl);
        }
        *(half8*)&lds_s[((t * 5 + 4) * 64 + lane) * 8] = av;

        // W' fragments (bf16): A[m=o][k=c]; o=col; row 8 = ones (normalizer)
#pragma unroll
        for (int q = 0; q < 2; ++q) {
            int k2 = 2 * t + q;
            short8 wf;
#pragma unroll
            for (int j = 0; j < 8; ++j) {
                int c2 = k2 * 16 + h * 8 + j;  // natural order (perm self-inverts)
                float val = (col < NO) ? W[c2 * NO + col] : (col == 8 ? 1.0f : 0.0f);
                wf[j] = (short)f2bf(val);
            }
            *(short8*)&lds_s[WOFF + (k2 * 64 + lane) * 8] = wf;
        }
    }

    // ---- convert x row: fp16 fragments, xsq, affine pair f12 ----
    half8 xh0, xh1, xh2, xh3, f12;
    {
        float part = 0.0f;
        half8 hv[4];
#pragma unroll
        for (int kd = 0; kd < 4; ++kd) {
            float4 v0 = xr[2 * kd], v1 = xr[2 * kd + 1];
            float v[8] = {v0.x, v0.y, v0.z, v0.w, v1.x, v1.y, v1.z, v1.w};
            half8 hh;
#pragma unroll
            for (int j = 0; j < 8; ++j) {
                part = fmaf(v[j], v[j], part);
                hh[j] = (_Float16)v[j];
            }
            hv[kd] = hh;
        }
        xh0 = hv[0]; xh1 = hv[1]; xh2 = hv[2]; xh3 = hv[3];
        float xsq = part + __shfl_xor(part, 32, 64);
        float sh = (float)(_Float16)xsq;
        float sl = xsq - sh;
        half8 f;
#pragma unroll
        for (int j = 0; j < 8; ++j) f[j] = (_Float16)0.0f;
        if (h == 0) {
            f[0] = (_Float16)sh;
            f[1] = (_Float16)sl;
            f[2] = (_Float16)sh;
            f[3] = (_Float16)1.0f;
            f[4] = (_Float16)1.0f;
        }
        f12 = f;
    }

    __syncthreads();

    floatx16 acc2;
#pragma unroll
    for (int i = 0; i < 16; ++i) acc2[i] = 0.0f;

#pragma unroll 2
    for (int t = 0; t < 8; ++t) {
        const half8 A0 = *(const half8*)&lds_s[((t * 5 + 0) * 64 + lane) * 8];
        const half8 A1 = *(const half8*)&lds_s[((t * 5 + 1) * 64 + lane) * 8];
        const half8 A2 = *(const half8*)&lds_s[((t * 5 + 2) * 64 + lane) * 8];
        const half8 A3 = *(const half8*)&lds_s[((t * 5 + 3) * 64 + lane) * 8];
        const half8 C12 = *(const half8*)&lds_s[((t * 5 + 4) * 64 + lane) * 8];
        const short8 w0 = *(const short8*)&lds_s[WOFF + ((2 * t + 0) * 64 + lane) * 8];
        const short8 w1 = *(const short8*)&lds_s[WOFF + ((2 * t + 1) * 64 + lane) * 8];

        floatx16 acc;
#pragma unroll
        for (int i = 0; i < 16; ++i) acc[i] = 0.0f;
        acc = __builtin_amdgcn_mfma_f32_32x32x16_f16(A0, xh0, acc, 0, 0, 0);
        acc = __builtin_amdgcn_mfma_f32_32x32x16_f16(A1, xh1, acc, 0, 0, 0);
        acc = __builtin_amdgcn_mfma_f32_32x32x16_f16(A2, xh2, acc, 0, 0, 0);
        acc = __builtin_amdgcn_mfma_f32_32x32x16_f16(A3, xh3, acc, 0, 0, 0);
        acc = __builtin_amdgcn_mfma_f32_32x32x16_f16(C12, f12, acc, 0, 0, 0);

        // exp2 -> bf16 (RTZ) two-at-a-time via v_perm
        unsigned p0 = __builtin_bit_cast(unsigned, __builtin_amdgcn_exp2f(acc[0]));
        unsigned p1 = __builtin_bit_cast(unsigned, __builtin_amdgcn_exp2f(acc[1]));
        unsigned p2 = __builtin_bit_cast(unsigned, __builtin_amdgcn_exp2f(acc[2]));
        unsigned p3 = __builtin_bit_cast(unsigned, __builtin_amdgcn_exp2f(acc[3]));
        unsigned p4 = __builtin_bit_cast(unsigned, __builtin_amdgcn_exp2f(acc[4]));
        unsigned p5 = __builtin_bit_cast(unsigned, __builtin_amdgcn_exp2f(acc[5]));
        unsigned p6 = __builtin_bit_cast(unsigned, __builtin_amdgcn_exp2f(acc[6]));
        unsigned p7 = __builtin_bit_cast(unsigned, __builtin_amdgcn_exp2f(acc[7]));
        unsigned p8 = __builtin_bit_cast(unsigned, __builtin_amdgcn_exp2f(acc[8]));
        unsigned p9 = __builtin_bit_cast(unsigned, __builtin_amdgcn_exp2f(acc[9]));
        unsigned pa = __builtin_bit_cast(unsigned, __builtin_amdgcn_exp2f(acc[10]));
        unsigned pb = __builtin_bit_cast(unsigned, __builtin_amdgcn_exp2f(acc[11]));
        unsigned pc = __builtin_bit_cast(unsigned, __builtin_amdgcn_exp2f(acc[12]));
        unsigned pd = __builtin_bit_cast(unsigned, __builtin_amdgcn_exp2f(acc[13]));
        unsigned pe = __builtin_bit_cast(unsigned, __builtin_amdgcn_exp2f(acc[14]));
        unsigned pf = __builtin_bit_cast(unsigned, __builtin_amdgcn_exp2f(acc[15]));
        uint4 q0, q1;
        q0.x = __builtin_amdgcn_perm(p1, p0, 0x07060302u);
        q0.y = __builtin_amdgcn_perm(p3, p2, 0x07060302u);
        q0.z = __builtin_amdgcn_perm(p5, p4, 0x07060302u);
        q0.w = __builtin_amdgcn_perm(p7, p6, 0x07060302u);
        q1.x = __builtin_amdgcn_perm(p9, p8, 0x07060302u);
        q1.y = __builtin_amdgcn_perm(pb, pa, 0x07060302u);
        q1.z = __builtin_amdgcn_perm(pd, pc, 0x07060302u);
        q1.w = __builtin_amdgcn_perm(pf, pe, 0x07060302u);
        short8 pf0 = __builtin_bit_cast(short8, q0);
        short8 pf1 = __builtin_bit_cast(short8, q1);

        acc2 = __builtin_amdgcn_mfma_f32_32x32x16_bf16(w0, pf0, acc2, 0, 0, 0);
        acc2 = __builtin_amdgcn_mfma_f32_32x32x16_bf16(w1, pf1, acc2, 0, 0, 0);
    }

    // ---- epilogue ----
    {
        float S = acc2[4];  // row 8 (normalizer) lives at h==0, reg 4
        float Sp = __shfl_xor(S, 32, 64);
        if (h) S = Sp;
        float inv = 1.0f / S;
        float4 r;
        r.x = acc2[0] * inv;
        r.y = acc2[1] * inv;
        r.z = acc2[2] * inv;
        r.w = acc2[3] * inv;
        // h=0 lanes hold o=0..3, h=1 lanes hold o=4..7 of the same b
        ((float4*)(out + (size_t)b * NO))[h] = r;
    }
}

extern "C" void kernel_launch(void* const* d_in, const int* in_sizes, int n_in,
                              void* d_out, int out_size, void* d_ws, size_t ws_size,
                              hipStream_t stream) {
    const float* x       = (const float*)d_in[0];  // [B, D]
    const float* centers = (const float*)d_in[1];  // [C, D]
    const float* widths  = (const float*)d_in[2];  // [C]
    const float* W       = (const float*)d_in[3];  // [C, O]
    float* out = (float*)d_out;
    (void)d_ws; (void)ws_size;

    // 1024 blocks x 512 threads; each wave: 32 b-columns + builds 1/8 of frags.
    // 2 resident blocks/CU, 4 generations -> block-turnover phase overlap.
    fuzzy_main<<<NB / 256, 512, 0, stream>>>(x, centers, widths, W, out);
}

// Round 10
// 110.095 us; speedup vs baseline: 1.3541x; 1.0156x over previous
//
#include <hip/hip_runtime.h>

// FuzzySystemLayer, single fused kernel, 2 b-tiles/wave with 1-deep prefetch.
// B=262144, C=256, D=64, O=8 (fp32).
// GEMM1 in fp16 (32x32x16_f16): acc[c_row, b_col] = log2-domain exponent
//   e = (2*x.c)*k - k*x^2 - k*c^2,  k = log2(e)/(2 w^2)
//   5 K-blocks: 4x [A=fp16(2k*c) x B=fp16(x)] + 1 affine block (hi/lo fp16
//   splits of k, x^2, k*c^2; pair error ~2^-22).
// GEMM2 in bf16 (memb spans 2^-40..2^-200: fp16 would flush to zero).
//   out2[o,b] = W'^T @ memb, W' row 8 = ones -> normalizer.
// Cluster rows permuted by swap23 so exp2(acc) registers ARE GEMM2 B-fragments.
// R2: no local array indexed by runtime var (scratch demotion).
// R4: fragment loads from L2 were the latency wall -> LDS staging.
// R6: x B-slice is h-dependent: float4 idx 4*kd + 2*h (+1).
// R7/R9: phase-aligned load->barrier->compute ADDS phases (~28 us kernel).
// R8: 4-deep register pipelining spilled (2xRaw8+2xXF live -> 100 MB scratch).
// R10: exactly 1-deep: tile1's 8 float4 loads (32 VGPR) in flight during
//   tile0's compute (unroll 1 to keep transients ~45). Peak ~120 regs < 128.

#define NB 262144
#define NC 256
#define ND 64
#define NO 8

typedef __attribute__((ext_vector_type(8))) short short8;
typedef __attribute__((ext_vector_type(8))) _Float16 half8;
typedef __attribute__((ext_vector_type(16))) float floatx16;

// LDS layout in shorts:
//   A (fp16):  ((t*5 + idx)*64 + lane)*8 + j   idx 0..3 = 2k*c, idx 4 = affine
//   W (bf16):  20480 + (k2*64 + lane)*8 + j    k2 = 0..15
#define WOFF 20480
#define WS_SHORTS 28672  // 56 KB

__device__ inline unsigned short f2bf(float f) {
    unsigned u = __builtin_bit_cast(unsigned, f);
    u = u + 0x7FFFu + ((u >> 16) & 1u);
    return (unsigned short)(u >> 16);
}

struct Raw8 { float4 r0, r1, r2, r3, r4, r5, r6, r7; };
struct XF { half8 k0, k1, k2, k3, f12; };

__device__ __forceinline__ Raw8 load_x(const float* __restrict__ xrow, int h) {
    const float4* xp = (const float4*)xrow;
    Raw8 r;
    r.r0 = xp[0 + 2 * h];  r.r1 = xp[1 + 2 * h];
    r.r2 = xp[4 + 2 * h];  r.r3 = xp[5 + 2 * h];
    r.r4 = xp[8 + 2 * h];  r.r5 = xp[9 + 2 * h];
    r.r6 = xp[12 + 2 * h]; r.r7 = xp[13 + 2 * h];
    return r;
}

__device__ __forceinline__ half8 cvt8(float4 a, float4 b, float& part) {
    float v[8] = {a.x, a.y, a.z, a.w, b.x, b.y, b.z, b.w};
    half8 hh;
#pragma unroll
    for (int j = 0; j < 8; ++j) {
        part = fmaf(v[j], v[j], part);
        hh[j] = (_Float16)v[j];
    }
    return hh;
}

__device__ __forceinline__ XF convert_x(const Raw8& r, int h) {
    float part = 0.0f;
    XF f;
    f.k0 = cvt8(r.r0, r.r1, part);
    f.k1 = cvt8(r.r2, r.r3, part);
    f.k2 = cvt8(r.r4, r.r5, part);
    f.k3 = cvt8(r.r6, r.r7, part);
    float xsq = part + __shfl_xor(part, 32, 64);
    float sh = (float)(_Float16)xsq;
    float sl = xsq - sh;
    half8 ff;
#pragma unroll
    for (int j = 0; j < 8; ++j) ff[j] = (_Float16)0.0f;
    if (h == 0) {
        ff[0] = (_Float16)sh;
        ff[1] = (_Float16)sl;
        ff[2] = (_Float16)sh;
        ff[3] = (_Float16)1.0f;
        ff[4] = (_Float16)1.0f;
    }
    f.f12 = ff;
    return f;
}

// unroll 1 deliberately: keeps transient frag registers to ONE tile's worth
// so the in-flight prefetch Raw8 fits under the 128-VGPR cap (R8 lesson).
__device__ __forceinline__ void compute_btile(const short* lds_s, int lane, int h,
                                              const XF& xf, float* __restrict__ outp) {
    floatx16 acc2;
#pragma unroll
    for (int i = 0; i < 16; ++i) acc2[i] = 0.0f;

#pragma unroll 1
    for (int t = 0; t < 8; ++t) {
        const half8 A0 = *(const half8*)&lds_s[((t * 5 + 0) * 64 + lane) * 8];
        const half8 A1 = *(const half8*)&lds_s[((t * 5 + 1) * 64 + lane) * 8];
        const half8 A2 = *(const half8*)&lds_s[((t * 5 + 2) * 64 + lane) * 8];
        const half8 A3 = *(const half8*)&lds_s[((t * 5 + 3) * 64 + lane) * 8];
        const half8 C12 = *(const half8*)&lds_s[((t * 5 + 4) * 64 + lane) * 8];
        const short8 w0 = *(const short8*)&lds_s[WOFF + ((2 * t + 0) * 64 + lane) * 8];
        const short8 w1 = *(const short8*)&lds_s[WOFF + ((2 * t + 1) * 64 + lane) * 8];

        floatx16 acc;
#pragma unroll
        for (int i = 0; i < 16; ++i) acc[i] = 0.0f;
        acc = __builtin_amdgcn_mfma_f32_32x32x16_f16(A0, xf.k0, acc, 0, 0, 0);
        acc = __builtin_amdgcn_mfma_f32_32x32x16_f16(A1, xf.k1, acc, 0, 0, 0);
        acc = __builtin_amdgcn_mfma_f32_32x32x16_f16(A2, xf.k2, acc, 0, 0, 0);
        acc = __builtin_amdgcn_mfma_f32_32x32x16_f16(A3, xf.k3, acc, 0, 0, 0);
        acc = __builtin_amdgcn_mfma_f32_32x32x16_f16(C12, xf.f12, acc, 0, 0, 0);

        // exp2 -> bf16 (RTZ) two-at-a-time via v_perm
        unsigned p0 = __builtin_bit_cast(unsigned, __builtin_amdgcn_exp2f(acc[0]));
        unsigned p1 = __builtin_bit_cast(unsigned, __builtin_amdgcn_exp2f(acc[1]));
        unsigned p2 = __builtin_bit_cast(unsigned, __builtin_amdgcn_exp2f(acc[2]));
        unsigned p3 = __builtin_bit_cast(unsigned, __builtin_amdgcn_exp2f(acc[3]));
        unsigned p4 = __builtin_bit_cast(unsigned, __builtin_amdgcn_exp2f(acc[4]));
        unsigned p5 = __builtin_bit_cast(unsigned, __builtin_amdgcn_exp2f(acc[5]));
        unsigned p6 = __builtin_bit_cast(unsigned, __builtin_amdgcn_exp2f(acc[6]));
        unsigned p7 = __builtin_bit_cast(unsigned, __builtin_amdgcn_exp2f(acc[7]));
        unsigned p8 = __builtin_bit_cast(unsigned, __builtin_amdgcn_exp2f(acc[8]));
        unsigned p9 = __builtin_bit_cast(unsigned, __builtin_amdgcn_exp2f(acc[9]));
        unsigned pa = __builtin_bit_cast(unsigned, __builtin_amdgcn_exp2f(acc[10]));
        unsigned pb = __builtin_bit_cast(unsigned, __builtin_amdgcn_exp2f(acc[11]));
        unsigned pc = __builtin_bit_cast(unsigned, __builtin_amdgcn_exp2f(acc[12]));
        unsigned pd = __builtin_bit_cast(unsigned, __builtin_amdgcn_exp2f(acc[13]));
        unsigned pe = __builtin_bit_cast(unsigned, __builtin_amdgcn_exp2f(acc[14]));
        unsigned pf = __builtin_bit_cast(unsigned, __builtin_amdgcn_exp2f(acc[15]));
        uint4 q0, q1;
        q0.x = __builtin_amdgcn_perm(p1, p0, 0x07060302u);
        q0.y = __builtin_amdgcn_perm(p3, p2, 0x07060302u);
        q0.z = __builtin_amdgcn_perm(p5, p4, 0x07060302u);
        q0.w = __builtin_amdgcn_perm(p7, p6, 0x07060302u);
        q1.x = __builtin_amdgcn_perm(p9, p8, 0x07060302u);
        q1.y = __builtin_amdgcn_perm(pb, pa, 0x07060302u);
        q1.z = __builtin_amdgcn_perm(pd, pc, 0x07060302u);
        q1.w = __builtin_amdgcn_perm(pf, pe, 0x07060302u);
        short8 pf0 = __builtin_bit_cast(short8, q0);
        short8 pf1 = __builtin_bit_cast(short8, q1);

        acc2 = __builtin_amdgcn_mfma_f32_32x32x16_bf16(w0, pf0, acc2, 0, 0, 0);
        acc2 = __builtin_amdgcn_mfma_f32_32x32x16_bf16(w1, pf1, acc2, 0, 0, 0);
    }

    float S = acc2[4];  // row 8 (normalizer) lives at h==0, reg 4
    float Sp = __shfl_xor(S, 32, 64);
    if (h) S = Sp;
    float inv = 1.0f / S;
    float4 r;
    r.x = acc2[0] * inv;
    r.y = acc2[1] * inv;
    r.z = acc2[2] * inv;
    r.w = acc2[3] * inv;
    ((float4*)outp)[h] = r;  // h=0: o=0..3, h=1: o=4..7
}

__global__ __launch_bounds__(512, 4) void fuzzy_main(
    const float* __restrict__ x,
    const float* __restrict__ centers,
    const float* __restrict__ widths,
    const float* __restrict__ W,
    float* __restrict__ out) {
    __shared__ short lds_s[WS_SHORTS];

    const int tid = threadIdx.x;
    const int wave = tid >> 6;
    const int lane = tid & 63;
    const int col = lane & 31;
    const int h = lane >> 5;
    const int bbase = (blockIdx.x * 8 + wave) * 64;  // 64 b-columns per wave
    const int b0 = bbase + col;
    const int b1 = bbase + 32 + col;

    // ---- tile0 x loads first (consumed after prep) ----
    Raw8 raw0 = load_x(x + (size_t)b0 * ND, h);

    // ---- fused prep: wave t builds tile t's fragments into LDS ----
    {
        const int t = wave;
        // cluster at GEMM1 row `col` of tile t: swap bits 2<->3 (self-inverse)
        const int c = 32 * t + ((col & 19) | ((col & 4) << 1) | ((col & 8) >> 1));
        const float* cr = centers + c * ND;
        float vv[4][8];
        float part = 0.0f;
#pragma unroll
        for (int kd = 0; kd < 4; ++kd) {
            const float4* p = (const float4*)(cr + kd * 16 + h * 8);
            float4 a0 = p[0], a1 = p[1];
            vv[kd][0] = a0.x; vv[kd][1] = a0.y; vv[kd][2] = a0.z; vv[kd][3] = a0.w;
            vv[kd][4] = a1.x; vv[kd][5] = a1.y; vv[kd][6] = a1.z; vv[kd][7] = a1.w;
#pragma unroll
            for (int j = 0; j < 8; ++j) part = fmaf(vv[kd][j], vv[kd][j], part);
        }
        float csq = part + __shfl_xor(part, 32, 64);
        float w = widths[c];
        float kk = 1.4426950408889634f / (2.0f * w * w);  // log2(e)/(2w^2)

#pragma unroll
        for (int kd = 0; kd < 4; ++kd) {
            half8 ah;
#pragma unroll
            for (int j = 0; j < 8; ++j) ah[j] = (_Float16)(2.0f * kk * vv[kd][j]);
            *(half8*)&lds_s[((t * 5 + kd) * 64 + lane) * 8] = ah;
        }
        // affine block (idx 4), nonzero only on h==0:
        // A = [-k_h, -k_h, -k_l, -(kc^2)_h, -(kc^2)_l, 0,0,0]
        // pairs B = [x2_h, x2_l, x2_h, 1, 1, 0,0,0]
        half8 av;
#pragma unroll
        for (int j = 0; j < 8; ++j) av[j] = (_Float16)0.0f;
        if (h == 0) {
            float kh = (float)(_Float16)kk;
            float kl = kk - kh;
            float Bc = csq * kk;
            float Bh = (float)(_Float16)Bc;
            float Bl = Bc - Bh;
            av[0] = (_Float16)(-kh);
            av[1] = (_Float16)(-kh);
            av[2] = (_Float16)(-kl);
            av[3] = (_Float16)(-Bh);
            av[4] = (_Float16)(-Bl);
        }
        *(half8*)&lds_s[((t * 5 + 4) * 64 + lane) * 8] = av;

        // W' fragments (bf16): A[m=o][k=c]; o=col; row 8 = ones (normalizer)
#pragma unroll
        for (int q = 0; q < 2; ++q) {
            int k2 = 2 * t + q;
            short8 wf;
#pragma unroll
            for (int j = 0; j < 8; ++j) {
                int c2 = k2 * 16 + h * 8 + j;  // natural order (perm self-inverts)
                float val = (col < NO) ? W[c2 * NO + col] : (col == 8 ? 1.0f : 0.0f);
                wf[j] = (short)f2bf(val);
            }
            *(short8*)&lds_s[WOFF + (k2 * 64 + lane) * 8] = wf;
        }
    }

    // ---- prefetch tile1's x (in flight across tile0's compute) ----
    Raw8 raw1 = load_x(x + (size_t)b1 * ND, h);

    XF xf0 = convert_x(raw0, h);  // waits on raw0 only
    __syncthreads();

    compute_btile(lds_s, lane, h, xf0, out + (size_t)b0 * NO);

    XF xf1 = convert_x(raw1, h);  // raw1 dies here
    compute_btile(lds_s, lane, h, xf1, out + (size_t)b1 * NO);
}

extern "C" void kernel_launch(void* const* d_in, const int* in_sizes, int n_in,
                              void* d_out, int out_size, void* d_ws, size_t ws_size,
                              hipStream_t stream) {
    const float* x       = (const float*)d_in[0];  // [B, D]
    const float* centers = (const float*)d_in[1];  // [C, D]
    const float* widths  = (const float*)d_in[2];  // [C]
    const float* W       = (const float*)d_in[3];  // [C, O]
    float* out = (float*)d_out;
    (void)d_ws; (void)ws_size;

    // 512 blocks x 512 threads, all resident (2 blocks/CU); each wave: 64
    // b-columns as 2 tiles with 1-deep x prefetch bridging the phases.
    fuzzy_main<<<NB / 512, 512, 0, stream>>>(x, centers, widths, W, out);
}